// Round 1
// baseline (76.543 us; speedup 1.0000x reference)
//
#include <hip/hip_runtime.h>

// Problem constants (fixed by reference)
constexpr int B = 4, T = 8, V = 256, F = 64;
constexpr int BT = B * T;            // 32 (b,t) slices
constexpr int CHUNK = 8;             // rows of i per block (R3/R5 sweet spot)
constexpr int NCHUNK = V / CHUNK;    // 32 -> grid = 32*32 = 1024 blocks (4 blocks/CU)
constexpr int K4 = F / 4;            // 16 float4 chunks per row

typedef float v2f __attribute__((ext_vector_type(2)));

// R7: the per-thread column stream x[j][0..63] was the last uncoalesced
// access: 16 x global_load_dwordx4 with 256B inter-lane stride = 64 cache
// lines touched per wave-load (4KB fetched per 1KB used), L2-latency bound
// with only 16 waves/CU. Fix: pre-transpose each [V][16]-of-float4 slice to
// XT4[bt][16][V] in d_ws (2MB, L3-resident, ~1-2us) so kernel B's column
// loads are unit-stride across lanes (16 fully-used lines per wave-load).
// Math in kernel B is bit-identical to R6 (same floats, same order).
__global__ __launch_bounds__(256)
void xpose(const float4* __restrict__ X4, float4* __restrict__ XT4)
{
    // One float4 per thread. Writes coalesced (consecutive o -> consecutive v).
    // Reads are strided but total only 2MB against L2/L3 (~sub-us).
    const int o  = blockIdx.x * 256 + threadIdx.x;  // 0 .. BT*K4*V-1 (131072)
    const int bt = o >> 12;                          // / (K4*V = 4096)
    const int r  = o & 4095;
    const int k  = r >> 8;                           // / V
    const int v  = r & 255;
    XT4[o] = X4[(bt << 12) | (v << 4) | k];          // XT4[bt][k][v] = X4[bt][v][k]
}

// Block = (bt, 8-row chunk). Thread tid owns column j=tid.
// score(i,j) = sum_f |x_i[f]-x_j[f]|*a[f] is SYMMETRIC, so denom[i]
// (= column-i sum in the reference) equals the row-i sum -> block-local
// reduction, no grid sync / atomics / workspace.
//
// R5: row data via WAVE-UNIFORM global addresses -> s_load_dwordx4 (scalar
// pipe + scalar cache), no LDS staging.
// R6: packed-f32 inner loop (v_pk_sub / v_pk_max(neg) / v_pk_fma).
// R7: column stream from transposed XT4 -> coalesced global_load_dwordx4.
__global__ __launch_bounds__(256)
void gl_fused(const float* __restrict__ X, const float* __restrict__ A,
              const float4* __restrict__ XT4, float* __restrict__ OUT)
{
    const int tid = threadIdx.x;           // column j
    const int bt  = blockIdx.x / NCHUNK;
    const int ic  = blockIdx.x % NCHUNK;
    const int i0  = ic * CHUNK;

    const float* xbt = X + (size_t)bt * V * F;            // [256][64] tile
    const float4* xrow4 = reinterpret_cast<const float4*>(xbt + (size_t)i0 * F);
    // xrow4[r*(F/4) + k] = float4 of row i0+r, features 4k..4k+3 (uniform addr)

    __shared__ float wpart[4][CHUNK];      // per-wave partial row sums
    __shared__ float rden[CHUNK];          // reciprocal denominators

    // a -> uniform address, scalarized; keep as packed pairs
    v2f af2[F / 2];
#pragma unroll
    for (int k = 0; k < K4; ++k) {
        const float4 v = reinterpret_cast<const float4*>(A)[k];
        af2[2*k+0] = (v2f){v.x, v.y};
        af2[2*k+1] = (v2f){v.z, v.w};
    }

    v2f acc2[CHUNK];
#pragma unroll
    for (int r = 0; r < CHUNK; ++r) acc2[r] = (v2f){0.0f, 0.0f};

    // stream own column in float4 chunks from the transposed copy;
    // colp[k*V] = features 4k..4k+3 of column tid, unit-stride across lanes.
    const float4* colp = XT4 + (size_t)bt * (K4 * V) + tid;
#pragma unroll
    for (int k = 0; k < K4; ++k) {
        const float4 xv = colp[(size_t)k * V];
        const v2f xlo = (v2f){xv.x, xv.y};
        const v2f xhi = (v2f){xv.z, xv.w};
#pragma unroll
        for (int r = 0; r < CHUNK; ++r) {
            const float4 sr = xrow4[r * K4 + k];        // uniform -> s_load_dwordx4
            const v2f d0 = xlo - (v2f){sr.x, sr.y};     // v_pk_add (neg mod)
            const v2f d1 = xhi - (v2f){sr.z, sr.w};
            const v2f a0 = __builtin_elementwise_max(d0, -d0);  // v_pk_max (neg mod)
            const v2f a1 = __builtin_elementwise_max(d1, -d1);
            acc2[r] = __builtin_elementwise_fma(a0, af2[2*k+0], acc2[r]); // v_pk_fma
            acc2[r] = __builtin_elementwise_fma(a1, af2[2*k+1], acc2[r]);
        }
    }

    float tmp[CHUNK];
#pragma unroll
    for (int r = 0; r < CHUNK; ++r) {
        const float s = acc2[r].x + acc2[r].y;
        tmp[r] = __expf(fmaxf(s, 0.0f));
    }

    // block reduction: row sum = denominator (symmetry)
    const int lane = tid & 63;
    const int wv   = tid >> 6;
#pragma unroll
    for (int r = 0; r < CHUNK; ++r) {
        float v = tmp[r];
        v += __shfl_xor(v, 32);
        v += __shfl_xor(v, 16);
        v += __shfl_xor(v, 8);
        v += __shfl_xor(v, 4);
        v += __shfl_xor(v, 2);
        v += __shfl_xor(v, 1);
        if (lane == 0) wpart[wv][r] = v;
    }
    __syncthreads();
    if (tid < CHUNK) {
        const float d = wpart[0][tid] + wpart[1][tid] + wpart[2][tid] + wpart[3][tid];
        rden[tid] = 1.0f / d;
    }
    __syncthreads();

    // S[bt, i0+r, tid] = tmp[r] / denom[i0+r]; consecutive tids -> coalesced
    float* obase = OUT + (((size_t)bt * V + i0) * V) + tid;
#pragma unroll
    for (int r = 0; r < CHUNK; ++r)
        obase[(size_t)r * V] = tmp[r] * rden[r];
}

extern "C" void kernel_launch(void* const* d_in, const int* in_sizes, int n_in,
                              void* d_out, int out_size, void* d_ws, size_t ws_size,
                              hipStream_t stream)
{
    const float* X = (const float*)d_in[0];   // [B,T,V,F] fp32
    const float* A = (const float*)d_in[1];   // [F,1]     fp32
    float* OUT = (float*)d_out;               // [B,T,V,V] fp32

    float4* XT4 = (float4*)d_ws;              // [BT][K4][V] float4 = 2 MiB

    dim3 block(256);
    xpose<<<dim3(BT * K4 * V / 256), block, 0, stream>>>(
        (const float4*)X, XT4);
    gl_fused<<<dim3(BT * NCHUNK), block, 0, stream>>>(X, A, XT4, OUT);
}